// Round 1
// baseline (2623.142 us; speedup 1.0000x reference)
//
#include <hip/hip_runtime.h>
#include <math.h>

#define HSIZE (1u << 22)
#define HMASK (HSIZE - 1u)
#define KEMPTY 0xFFFFFFFFu

__device__ __forceinline__ float leakyf(float x) { return x >= 0.f ? x : 0.2f * x; }

// order-preserving float<->uint mapping for atomicMax on floats
__device__ __forceinline__ unsigned fenc(float f) {
    unsigned b = __float_as_uint(f);
    return (b & 0x80000000u) ? ~b : (b | 0x80000000u);
}
__device__ __forceinline__ float fdec(unsigned u) {
    unsigned b = (u & 0x80000000u) ? (u ^ 0x80000000u) : ~u;
    return __uint_as_float(b);
}

// ---------------- generic tiled fp32 GEMM ----------------
// C[M,TN] = epilogue(A @ W), W:[K,TN] row-major.
// AMODE 0: A[M,K] plain; AMODE 1: A = num[M,K], Aden[M] -> A/(den+1e-16)  (K==64 use)
// EPI 0: C = acc
// EPI 1: C = elu(acc + X + bias)        (X:[M,TN]; in-place C==X is safe per-element)
// EPI 2: C = relu(acc) + X
// EPI 3: C = acc; el[row]=rowdot(acc,avec[0:64]); er[row]=rowdot(acc,avec[64:128]) (TN==64)
template <int TN, int AMODE, int EPI>
__global__ __launch_bounds__(256) void gemm_k(
    const float* __restrict__ A, const float* __restrict__ Aden,
    const float* __restrict__ W, const float* __restrict__ X,
    const float* __restrict__ bias, const float* __restrict__ avec,
    float* __restrict__ el, float* __restrict__ er,
    float* __restrict__ C, int M, int K)
{
    constexpr int RT = 32;          // rows per block
    constexpr int KT = 64;          // K chunk
    constexpr int RL = 256 / TN;    // row lanes
    constexpr int RPT = RT / RL;    // rows per thread
    __shared__ float sW[KT][TN];
    __shared__ float sA[RT][KT];

    const int tid = threadIdx.x;
    const int c = tid % TN;
    const int rg = tid / TN;
    const int row0 = blockIdx.x * RT;

    float acc[RPT];
#pragma unroll
    for (int i = 0; i < RPT; ++i) acc[i] = 0.f;

    for (int k0 = 0; k0 < K; k0 += KT) {
        for (int idx = tid; idx < KT * TN; idx += 256) {
            int kk = idx / TN, nn = idx % TN;
            sW[kk][nn] = W[(size_t)(k0 + kk) * TN + nn];
        }
        for (int idx = tid; idx < RT * KT; idx += 256) {
            int rr = idx / KT, kk = idx % KT;
            int row = row0 + rr;
            float v = 0.f;
            if (row < M) {
                v = A[(size_t)row * K + k0 + kk];
                if (AMODE == 1) v /= (Aden[row] + 1e-16f);
            }
            sA[rr][kk] = v;
        }
        __syncthreads();
        for (int kk = 0; kk < KT; ++kk) {
            float wv = sW[kk][c];
#pragma unroll
            for (int i = 0; i < RPT; ++i)
                acc[i] += sA[rg + i * RL][kk] * wv;
        }
        __syncthreads();
    }

#pragma unroll
    for (int i = 0; i < RPT; ++i) {
        int row = row0 + rg + i * RL;
        if (row >= M) continue;  // uniform across the wave (wave covers one rg)
        float v = acc[i];
        size_t o = (size_t)row * TN + c;
        if (EPI == 0) {
            C[o] = v;
        } else if (EPI == 1) {
            float t = v + X[o] + bias[c];
            C[o] = t > 0.f ? t : expm1f(t);
        } else if (EPI == 2) {
            C[o] = (v > 0.f ? v : 0.f) + X[o];
        } else if (EPI == 3) {
            C[o] = v;
            float pl = v * avec[c];
            float ph = v * avec[64 + c];
#pragma unroll
            for (int s = 32; s; s >>= 1) {
                pl += __shfl_xor(pl, s, 64);
                ph += __shfl_xor(ph, s, 64);
            }
            if (c == 0) { el[row] = pl; er[row] = ph; }
        }
    }
}

// ---------------- user-graph attention ----------------
__global__ __launch_bounds__(256) void edge_score_max(
    const int* __restrict__ ei, int E,
    const float* __restrict__ el, const float* __restrict__ er,
    float* __restrict__ earr, unsigned* __restrict__ dmax)
{
    int e = blockIdx.x * 256 + threadIdx.x;
    if (e >= E) return;
    int src = ei[e], dst = ei[E + e];
    float v = leakyf(el[dst] + er[src]);
    earr[e] = v;
    atomicMax(&dmax[dst], fenc(v));
}

__global__ __launch_bounds__(256) void edge_acc(
    const int* __restrict__ ei, int E,
    const float* __restrict__ earr, const unsigned* __restrict__ dmax,
    const float* __restrict__ H1,
    float* __restrict__ num, float* __restrict__ den)
{
    int g = blockIdx.x * 4 + (threadIdx.x >> 6);
    int lane = threadIdx.x & 63;
    if (g >= E) return;
    int src = ei[g], dst = ei[E + g];
    float p = expf(earr[g] - fdec(dmax[dst]));
    atomicAdd(&num[(size_t)dst * 64 + lane], p * H1[(size_t)src * 64 + lane]);
    if (lane == 0) atomicAdd(&den[dst], p);
}

// ---------------- biz multi-graph attention ----------------
__global__ __launch_bounds__(64) void om_k(const float* __restrict__ omega, float* __restrict__ om)
{
    if (threadIdx.x == 0 && blockIdx.x == 0) {
        float m = fmaxf(omega[0], fmaxf(omega[1], omega[2]));
        float e0 = expf(omega[0] - m), e1 = expf(omega[1] - m), e2 = expf(omega[2] - m);
        float s = e0 + e1 + e2;
        om[0] = e0 / s; om[1] = e1 / s; om[2] = e2 / s;
    }
}

__global__ __launch_bounds__(256) void biz_build(
    const int* __restrict__ e0, const int* __restrict__ e1, const int* __restrict__ e2,
    int E, const float* __restrict__ om,
    unsigned* __restrict__ hkeys, float* __restrict__ hw)
{
    int t = blockIdx.x * 256 + threadIdx.x;
    if (t >= 3 * E) return;
    int g = t < E ? 0 : (t < 2 * E ? 1 : 2);
    int e = t - g * E;
    const int* ei = (g == 0) ? e0 : ((g == 1) ? e1 : e2);
    unsigned src = (unsigned)ei[e], dst = (unsigned)ei[E + e];
    unsigned key = (src << 16) | dst;   // both < 50000 < 2^16
    float w = om[g];
    unsigned h = (key * 2654435761u) >> 10;  // 22 high bits
    while (true) {
        unsigned prev = atomicCAS(&hkeys[h], KEMPTY, key);
        if (prev == KEMPTY || prev == key) { atomicAdd(&hw[h], w); break; }
        h = (h + 1) & HMASK;
    }
}

__global__ __launch_bounds__(256) void biz_scan(
    const unsigned* __restrict__ hkeys, const float* __restrict__ hw,
    const float* __restrict__ el, const float* __restrict__ er,
    float* __restrict__ hme, unsigned* __restrict__ dmax,
    unsigned* __restrict__ hlist, unsigned* __restrict__ hcnt)
{
    unsigned s = blockIdx.x * 256 + threadIdx.x;
    if (s >= HSIZE) return;
    unsigned key = hkeys[s];
    if (key == KEMPTY) return;
    unsigned src = key >> 16, dst = key & 0xFFFFu;
    float v = leakyf(hw[s] * (el[dst] + er[src]));
    hme[s] = v;
    atomicMax(&dmax[dst], fenc(v));
    unsigned i = atomicAdd(hcnt, 1u);
    hlist[i] = s;
}

__global__ __launch_bounds__(256) void biz_acc(
    const unsigned* __restrict__ hlist, const unsigned* __restrict__ hcnt,
    const unsigned* __restrict__ hkeys, const float* __restrict__ hme,
    const unsigned* __restrict__ dmax, const float* __restrict__ H1,
    float* __restrict__ num, float* __restrict__ den)
{
    unsigned g = blockIdx.x * 4 + (threadIdx.x >> 6);
    int lane = threadIdx.x & 63;
    if (g >= *hcnt) return;
    unsigned s = hlist[g];
    unsigned key = hkeys[s];
    unsigned src = key >> 16, dst = key & 0xFFFFu;
    float p = expf(hme[s] - fdec(dmax[dst]));
    atomicAdd(&num[(size_t)dst * 64 + lane], p * H1[(size_t)src * 64 + lane]);
    if (lane == 0) atomicAdd(&den[dst], p);
}

// ---------------- final prediction ----------------
__global__ __launch_bounds__(256) void pred_k(
    const int* __restrict__ uidx, const int* __restrict__ bidx,
    const float* __restrict__ U, const float* __restrict__ B,
    const float* __restrict__ bu, const float* __restrict__ bb,
    const float* __restrict__ bg, float* __restrict__ pred, int Q)
{
    int g = blockIdx.x * 4 + (threadIdx.x >> 6);
    int lane = threadIdx.x & 63;
    if (g >= Q) return;
    int u = uidx[g], b = bidx[g];
    float p = U[(size_t)u * 64 + lane] * B[(size_t)b * 64 + lane];
#pragma unroll
    for (int s = 32; s; s >>= 1) p += __shfl_xor(p, s, 64);
    if (lane == 0) {
        float logit = p + bu[u] + bb[b] + bg[0];
        float sg = 1.f / (1.f + expf(-logit));
        pred[g] = 4.f * sg + 1.f;  // (R_MAX-R_MIN)*sig + R_MIN
    }
}

extern "C" void kernel_launch(void* const* d_in, const int* in_sizes, int n_in,
                              void* d_out, int out_size, void* d_ws, size_t ws_size,
                              hipStream_t stream)
{
    const float* S_u   = (const float*)d_in[0];
    const float* S_b   = (const float*)d_in[1];
    const int* ei_u    = (const int*)d_in[2];
    const int* ei_b0   = (const int*)d_in[3];
    const int* ei_b1   = (const int*)d_in[4];
    const int* ei_b2   = (const int*)d_in[5];
    const int* uidx    = (const int*)d_in[6];
    const int* bidx    = (const int*)d_in[7];
    const float* W1_u  = (const float*)d_in[8];
    const float* W1_b  = (const float*)d_in[9];
    const float* a_u   = (const float*)d_in[10];
    const float* a_b   = (const float*)d_in[11];
    const float* omega = (const float*)d_in[12];
    const float* W2_u  = (const float*)d_in[13];
    const float* W2_us = (const float*)d_in[14];
    const float* b1_u  = (const float*)d_in[15];
    const float* W2_b  = (const float*)d_in[16];
    const float* W2_bs = (const float*)d_in[17];
    const float* b1_b  = (const float*)d_in[18];
    const float* W3_u  = (const float*)d_in[19];
    const float* W3_b  = (const float*)d_in[20];
    const float* H4_u  = (const float*)d_in[21];
    const float* H4_b  = (const float*)d_in[22];
    const float* bias_u = (const float*)d_in[23];
    const float* bias_b = (const float*)d_in[24];
    const float* bias_g = (const float*)d_in[25];

    const int NU = in_sizes[0] / 256;
    const int NB = in_sizes[1] / 256;
    const int EU = in_sizes[2] / 2;
    const int EB = in_sizes[3] / 2;
    const int Q  = in_sizes[6];

    float* out  = (float*)d_out;
    float* pred = out;
    float* Uo   = out + Q;
    float* Bo   = Uo + (size_t)NU * 64;

    // workspace carve
    char* wsp = (char*)d_ws;
    size_t off = 0;
    auto carve = [&](size_t bytes) -> void* {
        void* p = wsp + off;
        off += (bytes + 255) & ~(size_t)255;
        return p;
    };
    float* H1u    = (float*)carve((size_t)NU * 64 * 4);
    float* Tu     = (float*)carve((size_t)NU * 128 * 4);   // T_u, then H3_u in place
    float* H1b    = (float*)carve((size_t)NB * 64 * 4);
    float* Tb     = (float*)carve((size_t)NB * 128 * 4);
    float* el_u   = (float*)carve((size_t)NU * 4);
    float* er_u   = (float*)carve((size_t)NU * 4);
    float* el_b   = (float*)carve((size_t)NB * 4);
    float* er_b   = (float*)carve((size_t)NB * 4);
    float* earr   = (float*)carve((size_t)EU * 4);
    unsigned* dmaxu = (unsigned*)carve((size_t)NU * 4);
    float* denu   = (float*)carve((size_t)NU * 4);
    float* numu   = (float*)carve((size_t)NU * 64 * 4);
    unsigned* dmaxb = (unsigned*)carve((size_t)NB * 4);
    float* denb   = (float*)carve((size_t)NB * 4);
    float* numb   = (float*)carve((size_t)NB * 64 * 4);
    unsigned* hkeys = (unsigned*)carve((size_t)HSIZE * 4);
    float* hw     = (float*)carve((size_t)HSIZE * 4);
    float* hme    = (float*)carve((size_t)HSIZE * 4);
    unsigned* hlist = (unsigned*)carve((size_t)HSIZE * 4);
    unsigned* hcnt  = (unsigned*)carve(256);
    float* om     = (float*)carve(256);
    (void)ws_size; (void)n_in; (void)out_size;

    // re-init accumulators/hash every call (harness does not re-poison)
    hipMemsetAsync(dmaxu, 0, (size_t)NU * 4, stream);
    hipMemsetAsync(denu,  0, (size_t)NU * 4, stream);
    hipMemsetAsync(numu,  0, (size_t)NU * 64 * 4, stream);
    hipMemsetAsync(dmaxb, 0, (size_t)NB * 4, stream);
    hipMemsetAsync(denb,  0, (size_t)NB * 4, stream);
    hipMemsetAsync(numb,  0, (size_t)NB * 64 * 4, stream);
    hipMemsetAsync(hkeys, 0xFF, (size_t)HSIZE * 4, stream);
    hipMemsetAsync(hw,    0, (size_t)HSIZE * 4, stream);
    hipMemsetAsync(hcnt,  0, 256, stream);

    om_k<<<1, 64, 0, stream>>>(omega, om);

    dim3 b256(256);
    // stage 1: H1 (+el/er) and T
    gemm_k<64, 0, 3><<<dim3((NU + 31) / 32), b256, 0, stream>>>(
        S_u, nullptr, W1_u, nullptr, nullptr, a_u, el_u, er_u, H1u, NU, 256);
    gemm_k<64, 0, 3><<<dim3((NB + 31) / 32), b256, 0, stream>>>(
        S_b, nullptr, W1_b, nullptr, nullptr, a_b, el_b, er_b, H1b, NB, 256);
    gemm_k<128, 0, 0><<<dim3((NU + 31) / 32), b256, 0, stream>>>(
        S_u, nullptr, W2_us, nullptr, nullptr, nullptr, nullptr, nullptr, Tu, NU, 256);
    gemm_k<128, 0, 0><<<dim3((NB + 31) / 32), b256, 0, stream>>>(
        S_b, nullptr, W2_bs, nullptr, nullptr, nullptr, nullptr, nullptr, Tb, NB, 256);

    // user attention
    edge_score_max<<<dim3((EU + 255) / 256), b256, 0, stream>>>(ei_u, EU, el_u, er_u, earr, dmaxu);
    edge_acc<<<dim3((EU + 3) / 4), b256, 0, stream>>>(ei_u, EU, earr, dmaxu, H1u, numu, denu);

    // biz attention (dedup across 3 graphs via hash)
    biz_build<<<dim3((3 * EB + 255) / 256), b256, 0, stream>>>(ei_b0, ei_b1, ei_b2, EB, om, hkeys, hw);
    biz_scan<<<dim3(HSIZE / 256), b256, 0, stream>>>(hkeys, hw, el_b, er_b, hme, dmaxb, hlist, hcnt);
    biz_acc<<<dim3((3 * EB + 3) / 4), b256, 0, stream>>>(hlist, hcnt, hkeys, hme, dmaxb, H1b, numb, denb);

    // stage 2: H3 = elu(H2@W2 + T + b1)  (in place over T), then U/B outputs
    gemm_k<128, 1, 1><<<dim3((NU + 31) / 32), b256, 0, stream>>>(
        numu, denu, W2_u, Tu, b1_u, nullptr, nullptr, nullptr, Tu, NU, 64);
    gemm_k<128, 1, 1><<<dim3((NB + 31) / 32), b256, 0, stream>>>(
        numb, denb, W2_b, Tb, b1_b, nullptr, nullptr, nullptr, Tb, NB, 64);
    gemm_k<64, 0, 2><<<dim3((NU + 31) / 32), b256, 0, stream>>>(
        Tu, nullptr, W3_u, H4_u, nullptr, nullptr, nullptr, nullptr, Uo, NU, 128);
    gemm_k<64, 0, 2><<<dim3((NB + 31) / 32), b256, 0, stream>>>(
        Tb, nullptr, W3_b, H4_b, nullptr, nullptr, nullptr, nullptr, Bo, NB, 128);

    // final prediction
    pred_k<<<dim3((Q + 3) / 4), b256, 0, stream>>>(uidx, bidx, Uo, Bo, bias_u, bias_b, bias_g, pred, Q);
}

// Round 2
// 1594.756 us; speedup vs baseline: 1.6449x; 1.6449x over previous
//
#include <hip/hip_runtime.h>
#include <math.h>

#define HSIZE (1u << 22)
#define HMASK (HSIZE - 1u)
#define KEMPTY 0xFFFFFFFFu

__device__ __forceinline__ float leakyf(float x) { return x >= 0.f ? x : 0.2f * x; }

// ---------------- register-blocked fp32 GEMM ----------------
// C[M,TN] = epilogue(A @ W), W:[K,TN] row-major. Thread computes 4 rows x 8 cols.
// AMODE 0: A[M,K] plain; AMODE 1: A = num[M,K] scaled by 1/(den[row]+1e-16)
// EPI 0: C = acc
// EPI 1: C = elu(acc + X + bias)   (in-place C==X safe per-element)
// EPI 2: C = relu(acc) + X
// EPI 3: C = acc; el[row]=rowdot(acc,avec[0:64]); er[row]=rowdot(acc,avec[64:128]) (TN==64)
template <int TN, int AMODE, int EPI>
__global__ __launch_bounds__(256) void gemm_k(
    const float* __restrict__ A, const float* __restrict__ Aden,
    const float* __restrict__ W, const float* __restrict__ X,
    const float* __restrict__ bias, const float* __restrict__ avec,
    float* __restrict__ el, float* __restrict__ er,
    float* __restrict__ C, int M, int K)
{
    constexpr int TNV = TN / 8;      // threads along n (8 or 16)
    constexpr int TMV = 256 / TNV;   // threads along m (32 or 16)
    constexpr int RT  = TMV * 4;     // rows per block (128 or 64)
    constexpr int KT  = 32;          // K chunk
    __shared__ float sW[KT][TN];
    __shared__ float sA[RT][KT + 1];

    const int tid = threadIdx.x;
    const int tn = tid % TNV;
    const int tm = tid / TNV;
    const int c0 = tn * 8;
    const int r0l = tm * 4;
    const int row0 = blockIdx.x * RT;

    float acc[4][8];
#pragma unroll
    for (int i = 0; i < 4; ++i)
#pragma unroll
        for (int j = 0; j < 8; ++j) acc[i][j] = 0.f;

    for (int k0 = 0; k0 < K; k0 += KT) {
        for (int idx = tid; idx < KT * TN; idx += 256) {
            int kk = idx / TN, nn = idx % TN;
            sW[kk][nn] = W[(size_t)(k0 + kk) * TN + nn];
        }
        for (int idx = tid; idx < RT * KT; idx += 256) {
            int rr = idx / KT, kk = idx % KT;
            int row = row0 + rr;
            float v = 0.f;
            if (row < M) {
                v = A[(size_t)row * K + k0 + kk];
                if (AMODE == 1) v /= (Aden[row] + 1e-16f);
            }
            sA[rr][kk] = v;
        }
        __syncthreads();
#pragma unroll 4
        for (int kk = 0; kk < KT; ++kk) {
            float av[4];
#pragma unroll
            for (int i = 0; i < 4; ++i) av[i] = sA[r0l + i][kk];
            float wv[8];
            *(float4*)&wv[0] = *(const float4*)&sW[kk][c0];
            *(float4*)&wv[4] = *(const float4*)&sW[kk][c0 + 4];
#pragma unroll
            for (int i = 0; i < 4; ++i)
#pragma unroll
                for (int j = 0; j < 8; ++j) acc[i][j] += av[i] * wv[j];
        }
        __syncthreads();
    }

#pragma unroll
    for (int i = 0; i < 4; ++i) {
        int row = row0 + r0l + i;
        if (row >= M) continue;
        size_t o = (size_t)row * TN + c0;
        if (EPI == 0) {
#pragma unroll
            for (int j = 0; j < 8; ++j) C[o + j] = acc[i][j];
        } else if (EPI == 1) {
#pragma unroll
            for (int j = 0; j < 8; ++j) {
                float t = acc[i][j] + X[o + j] + bias[c0 + j];
                C[o + j] = t > 0.f ? t : expm1f(t);
            }
        } else if (EPI == 2) {
#pragma unroll
            for (int j = 0; j < 8; ++j) {
                float v = acc[i][j];
                C[o + j] = (v > 0.f ? v : 0.f) + X[o + j];
            }
        } else if (EPI == 3) {
            float pl = 0.f, ph = 0.f;
#pragma unroll
            for (int j = 0; j < 8; ++j) {
                C[o + j] = acc[i][j];
                pl += acc[i][j] * avec[c0 + j];
                ph += acc[i][j] * avec[64 + c0 + j];
            }
#pragma unroll
            for (int s = 4; s; s >>= 1) {
                pl += __shfl_xor(pl, s, 8);
                ph += __shfl_xor(ph, s, 8);
            }
            if (tn == 0) { el[row] = pl; er[row] = ph; }
        }
    }
}

// ---------------- user-graph attention (fused, no max pass) ----------------
__global__ __launch_bounds__(256) void edge_reduce(
    const int* __restrict__ ei, int E,
    const float* __restrict__ el, const float* __restrict__ er,
    const float* __restrict__ H1,
    float* __restrict__ num, float* __restrict__ den)
{
    int w = (blockIdx.x * 256 + threadIdx.x) >> 6;
    int lane = threadIdx.x & 63;
    if (w >= E) return;
    int src = ei[w], dst = ei[E + w];
    float p = expf(leakyf(el[dst] + er[src]));
    atomicAdd(&num[(size_t)dst * 64 + lane], p * H1[(size_t)src * 64 + lane]);
    if (lane == 0) atomicAdd(&den[dst], p);
}

// ---------------- biz multi-graph attention ----------------
__global__ __launch_bounds__(64) void om_k(const float* __restrict__ omega, float* __restrict__ om)
{
    if (threadIdx.x == 0 && blockIdx.x == 0) {
        float m = fmaxf(omega[0], fmaxf(omega[1], omega[2]));
        float e0 = expf(omega[0] - m), e1 = expf(omega[1] - m), e2 = expf(omega[2] - m);
        float s = e0 + e1 + e2;
        om[0] = e0 / s; om[1] = e1 / s; om[2] = e2 / s;
    }
}

__global__ __launch_bounds__(256) void biz_build(
    const int* __restrict__ e0, const int* __restrict__ e1, const int* __restrict__ e2,
    int E, const float* __restrict__ om,
    unsigned* __restrict__ hkeys, float* __restrict__ hw)
{
    int t = blockIdx.x * 256 + threadIdx.x;
    if (t >= 3 * E) return;
    int g = t < E ? 0 : (t < 2 * E ? 1 : 2);
    int e = t - g * E;
    const int* ei = (g == 0) ? e0 : ((g == 1) ? e1 : e2);
    unsigned src = (unsigned)ei[e], dst = (unsigned)ei[E + e];
    unsigned key = (src << 16) | dst;   // both < 50000 < 2^16
    float w = om[g];
    unsigned h = (key * 2654435761u) >> 10;  // 22 high bits
    while (true) {
        unsigned prev = atomicCAS(&hkeys[h], KEMPTY, key);
        if (prev == KEMPTY || prev == key) { atomicAdd(&hw[h], w); break; }
        h = (h + 1) & HMASK;
    }
}

// scan hash table; for each occupied slot do the 64-wide accumulation inline
__global__ __launch_bounds__(256) void biz_reduce(
    const unsigned* __restrict__ hkeys, const float* __restrict__ hw,
    const float* __restrict__ el, const float* __restrict__ er,
    const float* __restrict__ H1,
    float* __restrict__ num, float* __restrict__ den)
{
    unsigned w = (blockIdx.x * 256 + threadIdx.x) >> 6;  // wave id
    int lane = threadIdx.x & 63;
    unsigned base = w * 64;
    unsigned key = hkeys[base + lane];
    float wt = (key != KEMPTY) ? hw[base + lane] : 0.f;
    unsigned long long bal = __ballot(key != KEMPTY);
    while (bal) {
        int b = __ffsll(bal) - 1;
        bal &= bal - 1;
        unsigned k = __shfl(key, b, 64);
        float wv = __shfl(wt, b, 64);
        unsigned src = k >> 16, dst = k & 0xFFFFu;
        float p = expf(leakyf(wv * (el[dst] + er[src])));
        atomicAdd(&num[(size_t)dst * 64 + lane], p * H1[(size_t)src * 64 + lane]);
        if (lane == b) atomicAdd(&den[dst], p);
    }
}

// ---------------- final prediction ----------------
__global__ __launch_bounds__(256) void pred_k(
    const int* __restrict__ uidx, const int* __restrict__ bidx,
    const float* __restrict__ U, const float* __restrict__ B,
    const float* __restrict__ bu, const float* __restrict__ bb,
    const float* __restrict__ bg, float* __restrict__ pred, int Q)
{
    int g = blockIdx.x * 4 + (threadIdx.x >> 6);
    int lane = threadIdx.x & 63;
    if (g >= Q) return;
    int u = uidx[g], b = bidx[g];
    float p = U[(size_t)u * 64 + lane] * B[(size_t)b * 64 + lane];
#pragma unroll
    for (int s = 32; s; s >>= 1) p += __shfl_xor(p, s, 64);
    if (lane == 0) {
        float logit = p + bu[u] + bb[b] + bg[0];
        float sg = 1.f / (1.f + expf(-logit));
        pred[g] = 4.f * sg + 1.f;
    }
}

extern "C" void kernel_launch(void* const* d_in, const int* in_sizes, int n_in,
                              void* d_out, int out_size, void* d_ws, size_t ws_size,
                              hipStream_t stream)
{
    const float* S_u   = (const float*)d_in[0];
    const float* S_b   = (const float*)d_in[1];
    const int* ei_u    = (const int*)d_in[2];
    const int* ei_b0   = (const int*)d_in[3];
    const int* ei_b1   = (const int*)d_in[4];
    const int* ei_b2   = (const int*)d_in[5];
    const int* uidx    = (const int*)d_in[6];
    const int* bidx    = (const int*)d_in[7];
    const float* W1_u  = (const float*)d_in[8];
    const float* W1_b  = (const float*)d_in[9];
    const float* a_u   = (const float*)d_in[10];
    const float* a_b   = (const float*)d_in[11];
    const float* omega = (const float*)d_in[12];
    const float* W2_u  = (const float*)d_in[13];
    const float* W2_us = (const float*)d_in[14];
    const float* b1_u  = (const float*)d_in[15];
    const float* W2_b  = (const float*)d_in[16];
    const float* W2_bs = (const float*)d_in[17];
    const float* b1_b  = (const float*)d_in[18];
    const float* W3_u  = (const float*)d_in[19];
    const float* W3_b  = (const float*)d_in[20];
    const float* H4_u  = (const float*)d_in[21];
    const float* H4_b  = (const float*)d_in[22];
    const float* bias_u = (const float*)d_in[23];
    const float* bias_b = (const float*)d_in[24];
    const float* bias_g = (const float*)d_in[25];

    const int NU = in_sizes[0] / 256;
    const int NB = in_sizes[1] / 256;
    const int EU = in_sizes[2] / 2;
    const int EB = in_sizes[3] / 2;
    const int Q  = in_sizes[6];

    float* out  = (float*)d_out;
    float* pred = out;
    float* Uo   = out + Q;
    float* Bo   = Uo + (size_t)NU * 64;

    char* wsp = (char*)d_ws;
    size_t off = 0;
    auto carve = [&](size_t bytes) -> void* {
        void* p = wsp + off;
        off += (bytes + 255) & ~(size_t)255;
        return p;
    };
    float* H1u    = (float*)carve((size_t)NU * 64 * 4);
    float* Tu     = (float*)carve((size_t)NU * 128 * 4);   // T_u, then H3_u in place
    float* H1b    = (float*)carve((size_t)NB * 64 * 4);
    float* Tb     = (float*)carve((size_t)NB * 128 * 4);
    float* el_u   = (float*)carve((size_t)NU * 4);
    float* er_u   = (float*)carve((size_t)NU * 4);
    float* el_b   = (float*)carve((size_t)NB * 4);
    float* er_b   = (float*)carve((size_t)NB * 4);
    float* denu   = (float*)carve((size_t)NU * 4);
    float* numu   = (float*)carve((size_t)NU * 64 * 4);
    float* denb   = (float*)carve((size_t)NB * 4);
    float* numb   = (float*)carve((size_t)NB * 64 * 4);
    unsigned* hkeys = (unsigned*)carve((size_t)HSIZE * 4);
    float* hw     = (float*)carve((size_t)HSIZE * 4);
    float* om     = (float*)carve(256);
    (void)ws_size; (void)n_in; (void)out_size;

    // re-init accumulators/hash every call
    hipMemsetAsync(denu,  0, (size_t)NU * 4, stream);
    hipMemsetAsync(numu,  0, (size_t)NU * 64 * 4, stream);
    hipMemsetAsync(denb,  0, (size_t)NB * 4, stream);
    hipMemsetAsync(numb,  0, (size_t)NB * 64 * 4, stream);
    hipMemsetAsync(hkeys, 0xFF, (size_t)HSIZE * 4, stream);
    hipMemsetAsync(hw,    0, (size_t)HSIZE * 4, stream);

    om_k<<<1, 64, 0, stream>>>(omega, om);

    dim3 b256(256);
    // stage 1: H1 (+el/er fused) and T = S@W2s
    gemm_k<64, 0, 3><<<dim3((NU + 127) / 128), b256, 0, stream>>>(
        S_u, nullptr, W1_u, nullptr, nullptr, a_u, el_u, er_u, H1u, NU, 256);
    gemm_k<64, 0, 3><<<dim3((NB + 127) / 128), b256, 0, stream>>>(
        S_b, nullptr, W1_b, nullptr, nullptr, a_b, el_b, er_b, H1b, NB, 256);
    gemm_k<128, 0, 0><<<dim3((NU + 63) / 64), b256, 0, stream>>>(
        S_u, nullptr, W2_us, nullptr, nullptr, nullptr, nullptr, nullptr, Tu, NU, 256);
    gemm_k<128, 0, 0><<<dim3((NB + 63) / 64), b256, 0, stream>>>(
        S_b, nullptr, W2_bs, nullptr, nullptr, nullptr, nullptr, nullptr, Tb, NB, 256);

    // user attention (single fused pass)
    edge_reduce<<<dim3((EU + 3) / 4), b256, 0, stream>>>(ei_u, EU, el_u, er_u, H1u, numu, denu);

    // biz attention: hash-dedup then single fused scan+reduce
    biz_build<<<dim3((3 * EB + 255) / 256), b256, 0, stream>>>(ei_b0, ei_b1, ei_b2, EB, om, hkeys, hw);
    biz_reduce<<<dim3(HSIZE / 256), b256, 0, stream>>>(hkeys, hw, el_b, er_b, H1b, numb, denb);

    // stage 2: H3 = elu(H2@W2 + T + b1) (in place over T), then U/B outputs
    gemm_k<128, 1, 1><<<dim3((NU + 63) / 64), b256, 0, stream>>>(
        numu, denu, W2_u, Tu, b1_u, nullptr, nullptr, nullptr, Tu, NU, 64);
    gemm_k<128, 1, 1><<<dim3((NB + 63) / 64), b256, 0, stream>>>(
        numb, denb, W2_b, Tb, b1_b, nullptr, nullptr, nullptr, Tb, NB, 64);
    gemm_k<64, 0, 2><<<dim3((NU + 127) / 128), b256, 0, stream>>>(
        Tu, nullptr, W3_u, H4_u, nullptr, nullptr, nullptr, nullptr, Uo, NU, 128);
    gemm_k<64, 0, 2><<<dim3((NB + 127) / 128), b256, 0, stream>>>(
        Tb, nullptr, W3_b, H4_b, nullptr, nullptr, nullptr, nullptr, Bo, NB, 128);

    pred_k<<<dim3((Q + 3) / 4), b256, 0, stream>>>(uidx, bidx, Uo, Bo, bias_u, bias_b, bias_g, pred, Q);
}

// Round 3
// 1504.467 us; speedup vs baseline: 1.7436x; 1.0600x over previous
//
#include <hip/hip_runtime.h>
#include <math.h>

#define HSIZE (1u << 22)
#define HMASK (HSIZE - 1u)
#define KEMPTY 0xFFFFFFFFu

__device__ __forceinline__ float leakyf(float x) { return x >= 0.f ? x : 0.2f * x; }

// ---------------- register-blocked fp32 GEMM ----------------
// C[M,TN] = epilogue(A @ W), W:[K,TN] row-major. Thread computes 4 rows x 8 cols.
// EPI 0: C = acc
// EPI 1: C = elu(acc + X + bias)   (in-place C==X safe per-element)
// EPI 2: C = relu(acc) + X
// EPI 3: C = acc; el[row]=rowdot(acc,avec[0:64]); er[row]=rowdot(acc,avec[64:128]) (TN==64)
template <int TN, int EPI>
__global__ __launch_bounds__(256) void gemm_k(
    const float* __restrict__ A,
    const float* __restrict__ W, const float* __restrict__ X,
    const float* __restrict__ bias, const float* __restrict__ avec,
    float* __restrict__ el, float* __restrict__ er,
    float* __restrict__ C, int M, int K)
{
    constexpr int TNV = TN / 8;      // threads along n (8 or 16)
    constexpr int TMV = 256 / TNV;   // threads along m (32 or 16)
    constexpr int RT  = TMV * 4;     // rows per block (128 or 64)
    constexpr int KT  = 32;          // K chunk
    __shared__ float sW[KT][TN];
    __shared__ float sA[RT][KT + 1];

    const int tid = threadIdx.x;
    const int tn = tid % TNV;
    const int tm = tid / TNV;
    const int c0 = tn * 8;
    const int r0l = tm * 4;
    const int row0 = blockIdx.x * RT;

    float acc[4][8];
#pragma unroll
    for (int i = 0; i < 4; ++i)
#pragma unroll
        for (int j = 0; j < 8; ++j) acc[i][j] = 0.f;

    for (int k0 = 0; k0 < K; k0 += KT) {
        for (int idx = tid; idx < KT * TN; idx += 256) {
            int kk = idx / TN, nn = idx % TN;
            sW[kk][nn] = W[(size_t)(k0 + kk) * TN + nn];
        }
        for (int idx = tid; idx < RT * KT; idx += 256) {
            int rr = idx / KT, kk = idx % KT;
            int row = row0 + rr;
            float v = 0.f;
            if (row < M) v = A[(size_t)row * K + k0 + kk];
            sA[rr][kk] = v;
        }
        __syncthreads();
#pragma unroll 4
        for (int kk = 0; kk < KT; ++kk) {
            float av[4];
#pragma unroll
            for (int i = 0; i < 4; ++i) av[i] = sA[r0l + i][kk];
            float wv[8];
            *(float4*)&wv[0] = *(const float4*)&sW[kk][c0];
            *(float4*)&wv[4] = *(const float4*)&sW[kk][c0 + 4];
#pragma unroll
            for (int i = 0; i < 4; ++i)
#pragma unroll
                for (int j = 0; j < 8; ++j) acc[i][j] += av[i] * wv[j];
        }
        __syncthreads();
    }

#pragma unroll
    for (int i = 0; i < 4; ++i) {
        int row = row0 + r0l + i;
        if (row >= M) continue;
        size_t o = (size_t)row * TN + c0;
        if (EPI == 0) {
#pragma unroll
            for (int j = 0; j < 8; ++j) C[o + j] = acc[i][j];
        } else if (EPI == 1) {
#pragma unroll
            for (int j = 0; j < 8; ++j) {
                float t = acc[i][j] + X[o + j] + bias[c0 + j];
                C[o + j] = t > 0.f ? t : expm1f(t);
            }
        } else if (EPI == 2) {
#pragma unroll
            for (int j = 0; j < 8; ++j) {
                float v = acc[i][j];
                C[o + j] = (v > 0.f ? v : 0.f) + X[o + j];
            }
        } else if (EPI == 3) {
            float pl = 0.f, ph = 0.f;
#pragma unroll
            for (int j = 0; j < 8; ++j) {
                C[o + j] = acc[i][j];
                pl += acc[i][j] * avec[c0 + j];
                ph += acc[i][j] * avec[64 + c0 + j];
            }
#pragma unroll
            for (int s = 4; s; s >>= 1) {
                pl += __shfl_xor(pl, s, 8);
                ph += __shfl_xor(ph, s, 8);
            }
            if (tn == 0) { el[row] = pl; er[row] = ph; }
        }
    }
}

// ---------------- CSR build: histogram + 3-kernel exclusive scan + scatter ----------------
__global__ __launch_bounds__(256) void hist_u(const int* __restrict__ ei, int E, int* __restrict__ cnt)
{
    int e = blockIdx.x * 256 + threadIdx.x;
    if (e >= E) return;
    atomicAdd(&cnt[ei[E + e]], 1);
}

__global__ __launch_bounds__(256) void scan_part(const int* __restrict__ cnt, int n, int* __restrict__ bsum)
{
    __shared__ int red[256];
    int base = blockIdx.x * 1024;
    int s = 0;
#pragma unroll
    for (int j = 0; j < 4; ++j) {
        int idx = base + threadIdx.x * 4 + j;
        if (idx < n) s += cnt[idx];
    }
    red[threadIdx.x] = s;
    __syncthreads();
    for (int st = 128; st; st >>= 1) {
        if (threadIdx.x < st) red[threadIdx.x] += red[threadIdx.x + st];
        __syncthreads();
    }
    if (threadIdx.x == 0) bsum[blockIdx.x] = red[0];
}

__global__ void scan_bsum(int* bsum, int nb)
{
    if (threadIdx.x == 0 && blockIdx.x == 0) {
        int run = 0;
        for (int i = 0; i < nb; ++i) { int v = bsum[i]; bsum[i] = run; run += v; }
    }
}

__global__ __launch_bounds__(256) void scan_final(const int* __restrict__ cnt, int n,
                                                  const int* __restrict__ bsum, int* __restrict__ rowp)
{
    __shared__ int tsum[256];
    int base = blockIdx.x * 1024;
    int tidx = threadIdx.x;
    int loc[4];
    int s = 0;
#pragma unroll
    for (int j = 0; j < 4; ++j) {
        int idx = base + tidx * 4 + j;
        loc[j] = (idx < n) ? cnt[idx] : 0;
        s += loc[j];
    }
    tsum[tidx] = s;
    __syncthreads();
    for (int st = 1; st < 256; st <<= 1) {
        int v = 0;
        if (tidx >= st) v = tsum[tidx - st];
        __syncthreads();
        if (tidx >= st) tsum[tidx] += v;
        __syncthreads();
    }
    int texc = tsum[tidx] - s + bsum[blockIdx.x];
#pragma unroll
    for (int j = 0; j < 4; ++j) {
        int idx = base + tidx * 4 + j;
        if (idx < n) { rowp[idx] = texc; texc += loc[j]; }
    }
}

__global__ __launch_bounds__(256) void scatter_u(const int* __restrict__ ei, int E,
                                                  int* __restrict__ rowp, int* __restrict__ ssrc)
{
    int e = blockIdx.x * 256 + threadIdx.x;
    if (e >= E) return;
    int src = ei[e], dst = ei[E + e];
    int pos = atomicAdd(&rowp[dst], 1);
    ssrc[pos] = src;
}

// one wave per destination: accumulate softmax-weighted neighbor features in registers
__global__ __launch_bounds__(256) void gather_u(
    const int* __restrict__ rowp, const int* __restrict__ cnt, const int* __restrict__ ssrc,
    const float* __restrict__ el, const float* __restrict__ er,
    const float* __restrict__ H1, float* __restrict__ H2, int N)
{
    int d = (blockIdx.x * 256 + threadIdx.x) >> 6;
    int lane = threadIdx.x & 63;
    if (d >= N) return;
    int end = rowp[d];           // post-scatter: rowp[d] == row end
    int start = end - cnt[d];
    float eld = el[d];
    float acc = 0.f, den = 0.f;
    for (int i = start; i < end; ++i) {
        int s = ssrc[i];
        float p = expf(leakyf(eld + er[s]));
        den += p;
        acc += p * H1[(size_t)s * 64 + lane];
    }
    H2[(size_t)d * 64 + lane] = acc / (den + 1e-16f);
}

// ---------------- biz multi-graph dedup (hash) + CSR ----------------
__global__ __launch_bounds__(64) void om_k(const float* __restrict__ omega, float* __restrict__ om)
{
    if (threadIdx.x == 0 && blockIdx.x == 0) {
        float m = fmaxf(omega[0], fmaxf(omega[1], omega[2]));
        float e0 = expf(omega[0] - m), e1 = expf(omega[1] - m), e2 = expf(omega[2] - m);
        float s = e0 + e1 + e2;
        om[0] = e0 / s; om[1] = e1 / s; om[2] = e2 / s;
    }
}

__global__ __launch_bounds__(256) void biz_build(
    const int* __restrict__ e0, const int* __restrict__ e1, const int* __restrict__ e2,
    int E, const float* __restrict__ om,
    unsigned* __restrict__ hkeys, float* __restrict__ hw)
{
    int t = blockIdx.x * 256 + threadIdx.x;
    if (t >= 3 * E) return;
    int g = t < E ? 0 : (t < 2 * E ? 1 : 2);
    int e = t - g * E;
    const int* ei = (g == 0) ? e0 : ((g == 1) ? e1 : e2);
    unsigned src = (unsigned)ei[e], dst = (unsigned)ei[E + e];
    unsigned key = (src << 16) | dst;   // both < 50000 < 2^16
    float w = om[g];
    unsigned h = (key * 2654435761u) >> 10;  // 22 high bits
    while (true) {
        unsigned prev = atomicCAS(&hkeys[h], KEMPTY, key);
        if (prev == KEMPTY || prev == key) { atomicAdd(&hw[h], w); break; }
        h = (h + 1) & HMASK;
    }
}

__global__ __launch_bounds__(256) void biz_hist(const unsigned* __restrict__ hkeys, int* __restrict__ cnt)
{
    unsigned s = blockIdx.x * 256 + threadIdx.x;
    unsigned key = hkeys[s];
    if (key == KEMPTY) return;
    atomicAdd(&cnt[key & 0xFFFFu], 1);
}

__global__ __launch_bounds__(256) void biz_scatter(
    const unsigned* __restrict__ hkeys, const float* __restrict__ hw,
    int* __restrict__ rowp, int* __restrict__ ssrc, float* __restrict__ sw)
{
    unsigned s = blockIdx.x * 256 + threadIdx.x;
    unsigned key = hkeys[s];
    if (key == KEMPTY) return;
    int pos = atomicAdd(&rowp[key & 0xFFFFu], 1);
    ssrc[pos] = (int)(key >> 16);
    sw[pos] = hw[s];
}

__global__ __launch_bounds__(256) void gather_b(
    const int* __restrict__ rowp, const int* __restrict__ cnt,
    const int* __restrict__ ssrc, const float* __restrict__ sw,
    const float* __restrict__ el, const float* __restrict__ er,
    const float* __restrict__ H1, float* __restrict__ H2, int N)
{
    int d = (blockIdx.x * 256 + threadIdx.x) >> 6;
    int lane = threadIdx.x & 63;
    if (d >= N) return;
    int end = rowp[d];
    int start = end - cnt[d];
    float eld = el[d];
    float acc = 0.f, den = 0.f;
    for (int i = start; i < end; ++i) {
        int s = ssrc[i];
        float p = expf(leakyf(sw[i] * (eld + er[s])));
        den += p;
        acc += p * H1[(size_t)s * 64 + lane];
    }
    H2[(size_t)d * 64 + lane] = acc / (den + 1e-16f);
}

// ---------------- final prediction ----------------
__global__ __launch_bounds__(256) void pred_k(
    const int* __restrict__ uidx, const int* __restrict__ bidx,
    const float* __restrict__ U, const float* __restrict__ B,
    const float* __restrict__ bu, const float* __restrict__ bb,
    const float* __restrict__ bg, float* __restrict__ pred, int Q)
{
    int g = blockIdx.x * 4 + (threadIdx.x >> 6);
    int lane = threadIdx.x & 63;
    if (g >= Q) return;
    int u = uidx[g], b = bidx[g];
    float p = U[(size_t)u * 64 + lane] * B[(size_t)b * 64 + lane];
#pragma unroll
    for (int s = 32; s; s >>= 1) p += __shfl_xor(p, s, 64);
    if (lane == 0) {
        float logit = p + bu[u] + bb[b] + bg[0];
        float sg = 1.f / (1.f + expf(-logit));
        pred[g] = 4.f * sg + 1.f;
    }
}

extern "C" void kernel_launch(void* const* d_in, const int* in_sizes, int n_in,
                              void* d_out, int out_size, void* d_ws, size_t ws_size,
                              hipStream_t stream)
{
    const float* S_u   = (const float*)d_in[0];
    const float* S_b   = (const float*)d_in[1];
    const int* ei_u    = (const int*)d_in[2];
    const int* ei_b0   = (const int*)d_in[3];
    const int* ei_b1   = (const int*)d_in[4];
    const int* ei_b2   = (const int*)d_in[5];
    const int* uidx    = (const int*)d_in[6];
    const int* bidx    = (const int*)d_in[7];
    const float* W1_u  = (const float*)d_in[8];
    const float* W1_b  = (const float*)d_in[9];
    const float* a_u   = (const float*)d_in[10];
    const float* a_b   = (const float*)d_in[11];
    const float* omega = (const float*)d_in[12];
    const float* W2_u  = (const float*)d_in[13];
    const float* W2_us = (const float*)d_in[14];
    const float* b1_u  = (const float*)d_in[15];
    const float* W2_b  = (const float*)d_in[16];
    const float* W2_bs = (const float*)d_in[17];
    const float* b1_b  = (const float*)d_in[18];
    const float* W3_u  = (const float*)d_in[19];
    const float* W3_b  = (const float*)d_in[20];
    const float* H4_u  = (const float*)d_in[21];
    const float* H4_b  = (const float*)d_in[22];
    const float* bias_u = (const float*)d_in[23];
    const float* bias_b = (const float*)d_in[24];
    const float* bias_g = (const float*)d_in[25];

    const int NU = in_sizes[0] / 256;
    const int NB = in_sizes[1] / 256;
    const int EU = in_sizes[2] / 2;
    const int EB = in_sizes[3] / 2;
    const int Q  = in_sizes[6];

    float* out  = (float*)d_out;
    float* pred = out;
    float* Uo   = out + Q;
    float* Bo   = Uo + (size_t)NU * 64;

    char* wsp = (char*)d_ws;
    size_t off = 0;
    auto carve = [&](size_t bytes) -> void* {
        void* p = wsp + off;
        off += (bytes + 255) & ~(size_t)255;
        return p;
    };
    float* H1u    = (float*)carve((size_t)NU * 64 * 4);
    float* Tu     = (float*)carve((size_t)NU * 128 * 4);   // T_u, then H3_u in place
    float* H1b    = (float*)carve((size_t)NB * 64 * 4);
    float* Tb     = (float*)carve((size_t)NB * 128 * 4);
    float* el_u   = (float*)carve((size_t)NU * 4);
    float* er_u   = (float*)carve((size_t)NU * 4);
    float* el_b   = (float*)carve((size_t)NB * 4);
    float* er_b   = (float*)carve((size_t)NB * 4);
    float* H2u    = (float*)carve((size_t)NU * 64 * 4);
    float* H2b    = (float*)carve((size_t)NB * 64 * 4);
    unsigned* hkeys = (unsigned*)carve((size_t)HSIZE * 4);
    float* hw     = (float*)carve((size_t)HSIZE * 4);
    int* cnt_u    = (int*)carve((size_t)NU * 4);
    int* rowp_u   = (int*)carve((size_t)NU * 4);
    int* su_src   = (int*)carve((size_t)EU * 4);
    int* cnt_b    = (int*)carve((size_t)NB * 4);
    int* rowp_b   = (int*)carve((size_t)NB * 4);
    int* sb_src   = (int*)carve((size_t)3 * EB * 4);
    float* sb_w   = (float*)carve((size_t)3 * EB * 4);
    int* bsum     = (int*)carve(1024);
    float* om     = (float*)carve(256);
    (void)ws_size; (void)n_in; (void)out_size;

    // re-init per call (harness does not re-poison)
    hipMemsetAsync(hkeys, 0xFF, (size_t)HSIZE * 4, stream);
    hipMemsetAsync(hw,    0, (size_t)HSIZE * 4, stream);
    hipMemsetAsync(cnt_u, 0, (size_t)NU * 4, stream);
    hipMemsetAsync(cnt_b, 0, (size_t)NB * 4, stream);

    om_k<<<1, 64, 0, stream>>>(omega, om);

    dim3 b256(256);
    // stage 1: H1 (+el/er fused) and T = S@W2s
    gemm_k<64, 3><<<dim3((NU + 127) / 128), b256, 0, stream>>>(
        S_u, W1_u, nullptr, nullptr, a_u, el_u, er_u, H1u, NU, 256);
    gemm_k<64, 3><<<dim3((NB + 127) / 128), b256, 0, stream>>>(
        S_b, W1_b, nullptr, nullptr, a_b, el_b, er_b, H1b, NB, 256);
    gemm_k<128, 0><<<dim3((NU + 63) / 64), b256, 0, stream>>>(
        S_u, W2_us, nullptr, nullptr, nullptr, nullptr, nullptr, Tu, NU, 256);
    gemm_k<128, 0><<<dim3((NB + 63) / 64), b256, 0, stream>>>(
        S_b, W2_bs, nullptr, nullptr, nullptr, nullptr, nullptr, Tb, NB, 256);

    // ---- user CSR + gather ----
    const int nb_u = (NU + 1023) / 1024;
    hist_u<<<dim3((EU + 255) / 256), b256, 0, stream>>>(ei_u, EU, cnt_u);
    scan_part<<<dim3(nb_u), b256, 0, stream>>>(cnt_u, NU, bsum);
    scan_bsum<<<1, 64, 0, stream>>>(bsum, nb_u);
    scan_final<<<dim3(nb_u), b256, 0, stream>>>(cnt_u, NU, bsum, rowp_u);
    scatter_u<<<dim3((EU + 255) / 256), b256, 0, stream>>>(ei_u, EU, rowp_u, su_src);
    gather_u<<<dim3((NU + 3) / 4), b256, 0, stream>>>(rowp_u, cnt_u, su_src, el_u, er_u, H1u, H2u, NU);

    // ---- biz hash dedup + CSR + gather ----
    const int nb_b = (NB + 1023) / 1024;
    biz_build<<<dim3((3 * EB + 255) / 256), b256, 0, stream>>>(ei_b0, ei_b1, ei_b2, EB, om, hkeys, hw);
    biz_hist<<<dim3(HSIZE / 256), b256, 0, stream>>>(hkeys, cnt_b);
    scan_part<<<dim3(nb_b), b256, 0, stream>>>(cnt_b, NB, bsum);
    scan_bsum<<<1, 64, 0, stream>>>(bsum, nb_b);
    scan_final<<<dim3(nb_b), b256, 0, stream>>>(cnt_b, NB, bsum, rowp_b);
    biz_scatter<<<dim3(HSIZE / 256), b256, 0, stream>>>(hkeys, hw, rowp_b, sb_src, sb_w);
    gather_b<<<dim3((NB + 3) / 4), b256, 0, stream>>>(rowp_b, cnt_b, sb_src, sb_w, el_b, er_b, H1b, H2b, NB);

    // stage 2: H3 = elu(H2@W2 + T + b1) (in place over T), then U/B outputs
    gemm_k<128, 1><<<dim3((NU + 63) / 64), b256, 0, stream>>>(
        H2u, W2_u, Tu, b1_u, nullptr, nullptr, nullptr, Tu, NU, 64);
    gemm_k<128, 1><<<dim3((NB + 63) / 64), b256, 0, stream>>>(
        H2b, W2_b, Tb, b1_b, nullptr, nullptr, nullptr, Tb, NB, 64);
    gemm_k<64, 2><<<dim3((NU + 127) / 128), b256, 0, stream>>>(
        Tu, W3_u, H4_u, nullptr, nullptr, nullptr, nullptr, Uo, NU, 128);
    gemm_k<64, 2><<<dim3((NB + 127) / 128), b256, 0, stream>>>(
        Tb, W3_b, H4_b, nullptr, nullptr, nullptr, nullptr, Bo, NB, 128);

    pred_k<<<dim3((Q + 3) / 4), b256, 0, stream>>>(uidx, bidx, Uo, Bo, bias_u, bias_b, bias_g, pred, Q);
}

// Round 4
// 839.860 us; speedup vs baseline: 3.1233x; 1.7913x over previous
//
#include <hip/hip_runtime.h>
#include <math.h>

__device__ __forceinline__ float leakyf(float x) { return x >= 0.f ? x : 0.2f * x; }

__device__ __forceinline__ unsigned short f2bf(float f) {
    unsigned u = __float_as_uint(f);
    u += 0x7FFFu + ((u >> 16) & 1u);   // RNE
    return (unsigned short)(u >> 16);
}
__device__ __forceinline__ float bf2f(unsigned short h) {
    return __uint_as_float(((unsigned)h) << 16);
}

typedef __attribute__((ext_vector_type(8))) short bf16x8;
typedef __attribute__((ext_vector_type(4))) float f32x4;

// ---------------- fp32 -> bf16 bulk convert (n multiple of 4) ----------------
__global__ __launch_bounds__(256) void conv_bf(const float* __restrict__ in,
                                               unsigned short* __restrict__ out, int n4)
{
    int i = blockIdx.x * 256 + threadIdx.x;
    if (i >= n4) return;
    float4 v = ((const float4*)in)[i];
    ushort4 o;
    o.x = f2bf(v.x); o.y = f2bf(v.y); o.z = f2bf(v.z); o.w = f2bf(v.w);
    ((ushort4*)out)[i] = o;
}

// ---------------- weight swizzle: fp32 [K][N] -> bf16 frag layout [N/16][K/8][16][8] ----------------
__global__ __launch_bounds__(256) void swz_w(const float* __restrict__ in,
                                             unsigned short* __restrict__ out, int K, int N)
{
    int idx = blockIdx.x * 256 + threadIdx.x;
    if (idx >= K * N) return;
    int k = idx / N, n = idx % N;
    out[(((n >> 4) * (K >> 3) + (k >> 3)) << 7) + ((n & 15) << 3) + (k & 7)] = f2bf(in[idx]);
}

// ---------------- MFMA GEMM: C[M,N] = epi(A[M,K] @ W[K,N]) ----------------
// A bf16 row-major; Wf swizzled bf16. One wave per 16-row strip, no LDS.
// EPI 0: C(bf16) = acc
// EPI 1: C(bf16) = elu(acc + Xbf16 + bias)
// EPI 2: C(f32)  = relu(acc) + Xf32
// EPI 3: C(f32)  = acc; el/er row-dots with avec (N==64)
template <int N, int EPI>
__global__ __launch_bounds__(256) void gemm_mfma(
    const unsigned short* __restrict__ A,
    const unsigned short* __restrict__ Wf,
    const void* __restrict__ Xv,
    const float* __restrict__ bias,
    const float* __restrict__ avec,
    float* __restrict__ el, float* __restrict__ er,
    void* __restrict__ Cv, int M, int K)
{
    const int lane = threadIdx.x & 63;
    const int wid = threadIdx.x >> 6;
    const int row0 = (blockIdx.x * 4 + wid) * 16;
    if (row0 >= M) return;          // M % 16 == 0 always
    constexpr int NT = N / 16;
    const int lr = lane & 15;       // A row offset / B col / C col
    const int lk = lane >> 4;       // k-group

    f32x4 acc[NT] = {};
    const unsigned short* Ap = A + (size_t)(row0 + lr) * K + lk * 8;
    const unsigned short* Bp = Wf + ((size_t)lk * 16 + lr) * 8;

    for (int k0 = 0; k0 < K; k0 += 32) {
        bf16x8 af = *(const bf16x8*)(Ap + k0);
#pragma unroll
        for (int nb = 0; nb < NT; ++nb) {
            bf16x8 bfr = *(const bf16x8*)(Bp + (size_t)(nb * (K >> 3) + (k0 >> 3)) * 128);
            acc[nb] = __builtin_amdgcn_mfma_f32_16x16x32_bf16(af, bfr, acc[nb], 0, 0, 0);
        }
    }

#pragma unroll
    for (int nb = 0; nb < NT; ++nb) {
        int col = nb * 16 + lr;
#pragma unroll
        for (int j = 0; j < 4; ++j) {
            int row = row0 + lk * 4 + j;
            size_t o = (size_t)row * N + col;
            float v = acc[nb][j];
            if (EPI == 0) {
                ((unsigned short*)Cv)[o] = f2bf(v);
            } else if (EPI == 1) {
                float t = v + bf2f(((const unsigned short*)Xv)[o]) + bias[col];
                ((unsigned short*)Cv)[o] = f2bf(t > 0.f ? t : expm1f(t));
            } else if (EPI == 2) {
                ((float*)Cv)[o] = (v > 0.f ? v : 0.f) + ((const float*)Xv)[o];
            } else {
                ((float*)Cv)[o] = v;
            }
        }
    }

    if (EPI == 3) {
        float pl[4] = {0, 0, 0, 0}, ph[4] = {0, 0, 0, 0};
#pragma unroll
        for (int nb = 0; nb < NT; ++nb) {
            float al = avec[nb * 16 + lr], ah = avec[64 + nb * 16 + lr];
#pragma unroll
            for (int j = 0; j < 4; ++j) { pl[j] += acc[nb][j] * al; ph[j] += acc[nb][j] * ah; }
        }
#pragma unroll
        for (int j = 0; j < 4; ++j) {
#pragma unroll
            for (int s = 8; s; s >>= 1) {
                pl[j] += __shfl_xor(pl[j], s, 16);
                ph[j] += __shfl_xor(ph[j], s, 16);
            }
        }
        if (lr == 0) {
#pragma unroll
            for (int j = 0; j < 4; ++j) {
                el[row0 + lk * 4 + j] = pl[j];
                er[row0 + lk * 4 + j] = ph[j];
            }
        }
    }
}

// ---------------- CSR build: histogram + 3-kernel exclusive scan + scatter ----------------
__global__ __launch_bounds__(256) void hist_u(const int* __restrict__ ei, int E, int* __restrict__ cnt)
{
    int e = blockIdx.x * 256 + threadIdx.x;
    if (e >= E) return;
    atomicAdd(&cnt[ei[E + e]], 1);
}

__global__ __launch_bounds__(256) void scan_part(const int* __restrict__ cnt, int n, int* __restrict__ bsum)
{
    __shared__ int red[256];
    int base = blockIdx.x * 1024;
    int s = 0;
#pragma unroll
    for (int j = 0; j < 4; ++j) {
        int idx = base + threadIdx.x * 4 + j;
        if (idx < n) s += cnt[idx];
    }
    red[threadIdx.x] = s;
    __syncthreads();
    for (int st = 128; st; st >>= 1) {
        if (threadIdx.x < st) red[threadIdx.x] += red[threadIdx.x + st];
        __syncthreads();
    }
    if (threadIdx.x == 0) bsum[blockIdx.x] = red[0];
}

__global__ void scan_bsum(int* bsum, int nb)
{
    if (threadIdx.x == 0 && blockIdx.x == 0) {
        int run = 0;
        for (int i = 0; i < nb; ++i) { int v = bsum[i]; bsum[i] = run; run += v; }
    }
}

__global__ __launch_bounds__(256) void scan_final(const int* __restrict__ cnt, int n,
                                                  const int* __restrict__ bsum, int* __restrict__ rowp)
{
    __shared__ int tsum[256];
    int base = blockIdx.x * 1024;
    int tidx = threadIdx.x;
    int loc[4];
    int s = 0;
#pragma unroll
    for (int j = 0; j < 4; ++j) {
        int idx = base + tidx * 4 + j;
        loc[j] = (idx < n) ? cnt[idx] : 0;
        s += loc[j];
    }
    tsum[tidx] = s;
    __syncthreads();
    for (int st = 1; st < 256; st <<= 1) {
        int v = 0;
        if (tidx >= st) v = tsum[tidx - st];
        __syncthreads();
        if (tidx >= st) tsum[tidx] += v;
        __syncthreads();
    }
    int texc = tsum[tidx] - s + bsum[blockIdx.x];
#pragma unroll
    for (int j = 0; j < 4; ++j) {
        int idx = base + tidx * 4 + j;
        if (idx < n) { rowp[idx] = texc; texc += loc[j]; }
    }
}

__global__ __launch_bounds__(256) void scatter_u(const int* __restrict__ ei, int E,
                                                 int* __restrict__ rowp, int* __restrict__ ssrc)
{
    int e = blockIdx.x * 256 + threadIdx.x;
    if (e >= E) return;
    int src = ei[e], dst = ei[E + e];
    int pos = atomicAdd(&rowp[dst], 1);
    ssrc[pos] = src;
}

// one wave per destination; no dedup (reference keeps user duplicates separate)
__global__ __launch_bounds__(256) void gather_u(
    const int* __restrict__ rowp, const int* __restrict__ cnt, const int* __restrict__ ssrc,
    const float* __restrict__ el, const float* __restrict__ er,
    const float* __restrict__ H1, unsigned short* __restrict__ H2, int N)
{
    int d = (blockIdx.x * 256 + threadIdx.x) >> 6;
    int lane = threadIdx.x & 63;
    if (d >= N) return;
    int end = rowp[d];          // post-scatter rowp[d] == row end
    int start = end - cnt[d];
    float eld = el[d];
    float acc = 0.f, den = 0.f;
    for (int i = start; i < end; ++i) {
        int s = ssrc[i];
        float p = expf(leakyf(eld + er[s]));
        den += p;
        acc += p * H1[(size_t)s * 64 + lane];
    }
    H2[(size_t)d * 64 + lane] = f2bf(acc / (den + 1e-16f));
}

// ---------------- biz multi-graph: CSR + in-row dedup ----------------
__global__ __launch_bounds__(64) void om_k(const float* __restrict__ omega, float* __restrict__ om)
{
    if (threadIdx.x == 0 && blockIdx.x == 0) {
        float m = fmaxf(omega[0], fmaxf(omega[1], omega[2]));
        float e0 = expf(omega[0] - m), e1 = expf(omega[1] - m), e2 = expf(omega[2] - m);
        float s = e0 + e1 + e2;
        om[0] = e0 / s; om[1] = e1 / s; om[2] = e2 / s;
    }
}

__global__ __launch_bounds__(256) void hist3(const int* __restrict__ e0, const int* __restrict__ e1,
                                             const int* __restrict__ e2, int E, int* __restrict__ cnt)
{
    int t = blockIdx.x * 256 + threadIdx.x;
    if (t >= 3 * E) return;
    int g = t < E ? 0 : (t < 2 * E ? 1 : 2);
    int e = t - g * E;
    const int* ei = (g == 0) ? e0 : ((g == 1) ? e1 : e2);
    atomicAdd(&cnt[ei[E + e]], 1);
}

__global__ __launch_bounds__(256) void scatter3(const int* __restrict__ e0, const int* __restrict__ e1,
                                                const int* __restrict__ e2, int E,
                                                const float* __restrict__ om, int* __restrict__ rowp,
                                                int* __restrict__ ssrc, float* __restrict__ sw)
{
    int t = blockIdx.x * 256 + threadIdx.x;
    if (t >= 3 * E) return;
    int g = t < E ? 0 : (t < 2 * E ? 1 : 2);
    int e = t - g * E;
    const int* ei = (g == 0) ? e0 : ((g == 1) ? e1 : e2);
    int src = ei[e], dst = ei[E + e];
    int pos = atomicAdd(&rowp[dst], 1);
    ssrc[pos] = src;
    sw[pos] = om[g];
}

// wave per dst: dedup (src groups), group-sum weights, masked softmax, accumulate
__global__ __launch_bounds__(256) void gather_b(
    const int* __restrict__ rowp, const int* __restrict__ cnt,
    const int* __restrict__ ssrc, const float* __restrict__ sw,
    const float* __restrict__ el, const float* __restrict__ er,
    const float* __restrict__ H1, unsigned short* __restrict__ H2, int N)
{
    int d = (blockIdx.x * 256 + threadIdx.x) >> 6;
    int lane = threadIdx.x & 63;
    if (d >= N) return;
    int end = rowp[d];
    int start = end - cnt[d];
    int L = end - start;
    float eld = el[d];
    float acc = 0.f, den;

    if (L <= 64) {
        int src = -1;
        float w = 0.f;
        if (lane < L) { src = ssrc[start + lane]; w = sw[start + lane]; }
        float W = 0.f;
        bool first = (lane < L);
        for (int k = 0; k < L; ++k) {
            int sk = __shfl(src, k, 64);
            float wk = __shfl(w, k, 64);
            if (lane < L && sk == src) {
                W += wk;
                if (k < lane) first = false;
            }
        }
        float p = 0.f;
        if (first) p = expf(leakyf(W * (eld + er[src])));
        den = p;
#pragma unroll
        for (int s = 32; s; s >>= 1) den += __shfl_xor(den, s, 64);
        for (int k = 0; k < L; ++k) {
            float pk = __shfl(p, k, 64);
            if (pk != 0.f) {
                int sk = __shfl(src, k, 64);
                acc += pk * H1[(size_t)sk * 64 + lane];
            }
        }
    } else {
        den = 0.f;
        for (int i = start; i < end; ++i) {
            int si = ssrc[i];
            float W = 0.f;
            bool first = true;
            for (int j = start + lane; j < end; j += 64) {
                if (ssrc[j] == si) {
                    W += sw[j];
                    if (j < i) first = false;
                }
            }
#pragma unroll
            for (int s = 32; s; s >>= 1) W += __shfl_xor(W, s, 64);
            first = __all(first);
            if (first) {
                float p = expf(leakyf(W * (eld + er[si])));
                den += p;
                acc += p * H1[(size_t)si * 64 + lane];
            }
        }
    }
    H2[(size_t)d * 64 + lane] = f2bf(acc / (den + 1e-16f));
}

// ---------------- final prediction ----------------
__global__ __launch_bounds__(256) void pred_k(
    const int* __restrict__ uidx, const int* __restrict__ bidx,
    const float* __restrict__ U, const float* __restrict__ B,
    const float* __restrict__ bu, const float* __restrict__ bb,
    const float* __restrict__ bg, float* __restrict__ pred, int Q)
{
    int g = blockIdx.x * 4 + (threadIdx.x >> 6);
    int lane = threadIdx.x & 63;
    if (g >= Q) return;
    int u = uidx[g], b = bidx[g];
    float p = U[(size_t)u * 64 + lane] * B[(size_t)b * 64 + lane];
#pragma unroll
    for (int s = 32; s; s >>= 1) p += __shfl_xor(p, s, 64);
    if (lane == 0) {
        float logit = p + bu[u] + bb[b] + bg[0];
        float sg = 1.f / (1.f + expf(-logit));
        pred[g] = 4.f * sg + 1.f;
    }
}

extern "C" void kernel_launch(void* const* d_in, const int* in_sizes, int n_in,
                              void* d_out, int out_size, void* d_ws, size_t ws_size,
                              hipStream_t stream)
{
    const float* S_u   = (const float*)d_in[0];
    const float* S_b   = (const float*)d_in[1];
    const int* ei_u    = (const int*)d_in[2];
    const int* ei_b0   = (const int*)d_in[3];
    const int* ei_b1   = (const int*)d_in[4];
    const int* ei_b2   = (const int*)d_in[5];
    const int* uidx    = (const int*)d_in[6];
    const int* bidx    = (const int*)d_in[7];
    const float* W1_u  = (const float*)d_in[8];
    const float* W1_b  = (const float*)d_in[9];
    const float* a_u   = (const float*)d_in[10];
    const float* a_b   = (const float*)d_in[11];
    const float* omega = (const float*)d_in[12];
    const float* W2_u  = (const float*)d_in[13];
    const float* W2_us = (const float*)d_in[14];
    const float* b1_u  = (const float*)d_in[15];
    const float* W2_b  = (const float*)d_in[16];
    const float* W2_bs = (const float*)d_in[17];
    const float* b1_b  = (const float*)d_in[18];
    const float* W3_u  = (const float*)d_in[19];
    const float* W3_b  = (const float*)d_in[20];
    const float* H4_u  = (const float*)d_in[21];
    const float* H4_b  = (const float*)d_in[22];
    const float* bias_u = (const float*)d_in[23];
    const float* bias_b = (const float*)d_in[24];
    const float* bias_g = (const float*)d_in[25];

    const int NU = in_sizes[0] / 256;
    const int NB = in_sizes[1] / 256;
    const int EU = in_sizes[2] / 2;
    const int EB = in_sizes[3] / 2;
    const int Q  = in_sizes[6];

    float* out  = (float*)d_out;
    float* pred = out;
    float* Uo   = out + Q;
    float* Bo   = Uo + (size_t)NU * 64;

    char* wsp = (char*)d_ws;
    size_t off = 0;
    auto carve = [&](size_t bytes) -> void* {
        void* p = wsp + off;
        off += (bytes + 255) & ~(size_t)255;
        return p;
    };
    // bf16 activations
    unsigned short* Subf = (unsigned short*)carve((size_t)NU * 256 * 2);  // dead after stage-1 -> H3u
    unsigned short* Sbbf = (unsigned short*)carve((size_t)NB * 256 * 2);  // dead after stage-1 -> H3b
    unsigned short* H3u  = Subf;   // alias: lifetimes disjoint (stream-ordered)
    unsigned short* H3b  = Sbbf;
    float* H1u  = (float*)carve((size_t)NU * 64 * 4);
    float* H1b  = (float*)carve((size_t)NB * 64 * 4);
    unsigned short* Tu  = (unsigned short*)carve((size_t)NU * 128 * 2);
    unsigned short* Tb  = (unsigned short*)carve((size_t)NB * 128 * 2);
    unsigned short* H2u = (unsigned short*)carve((size_t)NU * 64 * 2);
    unsigned short* H2b = (unsigned short*)carve((size_t)NB * 64 * 2);
    float* el_u = (float*)carve((size_t)NU * 4);
    float* er_u = (float*)carve((size_t)NU * 4);
    float* el_b = (float*)carve((size_t)NB * 4);
    float* er_b = (float*)carve((size_t)NB * 4);
    int* cnt_u  = (int*)carve((size_t)NU * 4);
    int* rowp_u = (int*)carve((size_t)NU * 4);
    int* su_src = (int*)carve((size_t)EU * 4);
    int* cnt_b  = (int*)carve((size_t)NB * 4);
    int* rowp_b = (int*)carve((size_t)NB * 4);
    int* sb_src = (int*)carve((size_t)3 * EB * 4);
    float* sb_w = (float*)carve((size_t)3 * EB * 4);
    int* bsum   = (int*)carve(1024);
    float* om   = (float*)carve(256);
    // swizzled bf16 weights
    unsigned short* w1u_s  = (unsigned short*)carve((size_t)256 * 64 * 2);
    unsigned short* w1b_s  = (unsigned short*)carve((size_t)256 * 64 * 2);
    unsigned short* w2us_s = (unsigned short*)carve((size_t)256 * 128 * 2);
    unsigned short* w2bs_s = (unsigned short*)carve((size_t)256 * 128 * 2);
    unsigned short* w2u_s  = (unsigned short*)carve((size_t)64 * 128 * 2);
    unsigned short* w2b_s  = (unsigned short*)carve((size_t)64 * 128 * 2);
    unsigned short* w3u_s  = (unsigned short*)carve((size_t)128 * 64 * 2);
    unsigned short* w3b_s  = (unsigned short*)carve((size_t)128 * 64 * 2);
    (void)ws_size; (void)n_in; (void)out_size;

    // per-call re-init (harness does not re-poison)
    hipMemsetAsync(cnt_u, 0, (size_t)NU * 4, stream);
    hipMemsetAsync(cnt_b, 0, (size_t)NB * 4, stream);

    dim3 b256(256);
    om_k<<<1, 64, 0, stream>>>(omega, om);

    // converts + weight swizzles
    conv_bf<<<dim3((NU * 64 + 255) / 256), b256, 0, stream>>>(S_u, Subf, NU * 64);      // NU*256/4
    conv_bf<<<dim3((NB * 64 + 255) / 256), b256, 0, stream>>>(S_b, Sbbf, NB * 64);
    swz_w<<<dim3((256 * 64 + 255) / 256), b256, 0, stream>>>(W1_u, w1u_s, 256, 64);
    swz_w<<<dim3((256 * 64 + 255) / 256), b256, 0, stream>>>(W1_b, w1b_s, 256, 64);
    swz_w<<<dim3((256 * 128 + 255) / 256), b256, 0, stream>>>(W2_us, w2us_s, 256, 128);
    swz_w<<<dim3((256 * 128 + 255) / 256), b256, 0, stream>>>(W2_bs, w2bs_s, 256, 128);
    swz_w<<<dim3((64 * 128 + 255) / 256), b256, 0, stream>>>(W2_u, w2u_s, 64, 128);
    swz_w<<<dim3((64 * 128 + 255) / 256), b256, 0, stream>>>(W2_b, w2b_s, 64, 128);
    swz_w<<<dim3((128 * 64 + 255) / 256), b256, 0, stream>>>(W3_u, w3u_s, 128, 64);
    swz_w<<<dim3((128 * 64 + 255) / 256), b256, 0, stream>>>(W3_b, w3b_s, 128, 64);

    // stage 1: H1 (+el/er fused, fp32 out) and T = S@W2s (bf16 out)
    gemm_mfma<64, 3><<<dim3((NU + 63) / 64), b256, 0, stream>>>(
        Subf, w1u_s, nullptr, nullptr, a_u, el_u, er_u, H1u, NU, 256);
    gemm_mfma<64, 3><<<dim3((NB + 63) / 64), b256, 0, stream>>>(
        Sbbf, w1b_s, nullptr, nullptr, a_b, el_b, er_b, H1b, NB, 256);
    gemm_mfma<128, 0><<<dim3((NU + 63) / 64), b256, 0, stream>>>(
        Subf, w2us_s, nullptr, nullptr, nullptr, nullptr, nullptr, Tu, NU, 256);
    gemm_mfma<128, 0><<<dim3((NB + 63) / 64), b256, 0, stream>>>(
        Sbbf, w2bs_s, nullptr, nullptr, nullptr, nullptr, nullptr, Tb, NB, 256);

    // ---- user CSR + gather ----
    const int nb_u = (NU + 1023) / 1024;
    hist_u<<<dim3((EU + 255) / 256), b256, 0, stream>>>(ei_u, EU, cnt_u);
    scan_part<<<dim3(nb_u), b256, 0, stream>>>(cnt_u, NU, bsum);
    scan_bsum<<<1, 64, 0, stream>>>(bsum, nb_u);
    scan_final<<<dim3(nb_u), b256, 0, stream>>>(cnt_u, NU, bsum, rowp_u);
    scatter_u<<<dim3((EU + 255) / 256), b256, 0, stream>>>(ei_u, EU, rowp_u, su_src);
    gather_u<<<dim3((NU + 3) / 4), b256, 0, stream>>>(rowp_u, cnt_u, su_src, el_u, er_u, H1u, H2u, NU);

    // ---- biz CSR (dst-binned, per-row dedup) + gather ----
    const int nb_b = (NB + 1023) / 1024;
    hist3<<<dim3((3 * EB + 255) / 256), b256, 0, stream>>>(ei_b0, ei_b1, ei_b2, EB, cnt_b);
    scan_part<<<dim3(nb_b), b256, 0, stream>>>(cnt_b, NB, bsum);
    scan_bsum<<<1, 64, 0, stream>>>(bsum, nb_b);
    scan_final<<<dim3(nb_b), b256, 0, stream>>>(cnt_b, NB, bsum, rowp_b);
    scatter3<<<dim3((3 * EB + 255) / 256), b256, 0, stream>>>(ei_b0, ei_b1, ei_b2, EB, om, rowp_b, sb_src, sb_w);
    gather_b<<<dim3((NB + 3) / 4), b256, 0, stream>>>(rowp_b, cnt_b, sb_src, sb_w, el_b, er_b, H1b, H2b, NB);

    // stage 2: H3 = elu(H2@W2 + T + b1) (bf16), then U/B outputs (fp32)
    gemm_mfma<128, 1><<<dim3((NU + 63) / 64), b256, 0, stream>>>(
        H2u, w2u_s, Tu, b1_u, nullptr, nullptr, nullptr, H3u, NU, 64);
    gemm_mfma<128, 1><<<dim3((NB + 63) / 64), b256, 0, stream>>>(
        H2b, w2b_s, Tb, b1_b, nullptr, nullptr, nullptr, H3b, NB, 64);
    gemm_mfma<64, 2><<<dim3((NU + 63) / 64), b256, 0, stream>>>(
        H3u, w3u_s, H4_u, nullptr, nullptr, nullptr, nullptr, Uo, NU, 128);
    gemm_mfma<64, 2><<<dim3((NB + 63) / 64), b256, 0, stream>>>(
        H3b, w3b_s, H4_b, nullptr, nullptr, nullptr, nullptr, Bo, NB, 128);

    pred_k<<<dim3((Q + 3) / 4), b256, 0, stream>>>(uidx, bidx, Uo, Bo, bias_u, bias_b, bias_g, pred, Q);
}